// Round 13
// baseline (1040.557 us; speedup 1.0000x reference)
//
#include <hip/hip_runtime.h>
#include <hip/hip_bf16.h>

#define B_ 64
#define T_ 256
#define H_ 1024
#define NB_ 256  // 4 groups x 64 col-blocks

typedef __attribute__((ext_vector_type(8))) short short8;
typedef __attribute__((ext_vector_type(4))) float float4_;
typedef unsigned long long u64;

static __device__ __forceinline__ ushort f2bf(float v) {
  __hip_bfloat16 b = __float2bfloat16(v);
  return *reinterpret_cast<ushort*>(&b);
}
static __device__ __forceinline__ float bf2f(ushort u) {
  unsigned int x = ((unsigned int)u) << 16;
  return __builtin_bit_cast(float, x);
}
static __device__ __forceinline__ float sigm(float v) { return 1.0f / (1.0f + __expf(-v)); }
static __device__ __forceinline__ float tanh_fast(float v) {
  float e = __expf(2.0f * v);
  return 1.0f - 2.0f / (e + 1.0f);
}
// sentinel = 0xFFFF (bf16 -NaN). h in (-1,1) never sets bit14 (needs |h|>=2),
// so the OR of data words can never be 0xFFFF -> check the OR of all 4.
static __device__ __forceinline__ bool hasS(u64 q) {
  return ((ushort)q == 0xFFFFu) | ((ushort)(q >> 16) == 0xFFFFu) |
         ((ushort)(q >> 32) == 0xFFFFu) | ((ushort)(q >> 48) == 0xFFFFu);
}

// Xall[t][b][j] bf16: j even = x[b][j/2][t], j odd = y[b][j/2][t-1] (0 at t=0)
__global__ __launch_bounds__(256) void build_X(const float* __restrict__ x,
                                               const float* __restrict__ y,
                                               ushort* __restrict__ Xall) {
  __shared__ float xl[128][33];
  __shared__ float yl[128][33];
  int b = blockIdx.x >> 3;
  int t0 = (blockIdx.x & 7) * 32;
  int tid = threadIdx.x;
  for (int it = 0; it < 16; ++it) {
    int idx = it * 256 + tid;
    int s = idx >> 5, tt = idx & 31;
    xl[s][tt] = x[((size_t)b * 128 + s) * T_ + t0 + tt];
    int ty = t0 + tt - 1;
    yl[s][tt] = (ty >= 0) ? y[((size_t)b * 128 + s) * T_ + ty] : 0.0f;
  }
  __syncthreads();
  for (int tt = 0; tt < 32; ++tt) {
    float v = (tid & 1) ? yl[tid >> 1][tt] : xl[tid >> 1][tt];
    Xall[((size_t)(t0 + tt) * B_ + b) * 256 + tid] = f2bf(v);
  }
}

// Bp[(((cbl*16 + w)*10 + u)*64 + l)*8 + j]
// wave w = ct*4+kq; frag u: kk = (u<2)? 2kq+u : 8+8kq+(u-2)
// lane l: B[k = 32kk + 8*(l>>4) + j][col_in_gate = cbl*16 + (l&15)], gate ct
__global__ __launch_bounds__(256) void prep_weights(const float* __restrict__ Wf,
                                                    const float* __restrict__ Wi,
                                                    const float* __restrict__ Wu,
                                                    const float* __restrict__ Wo,
                                                    ushort* __restrict__ Bp) {
  int flat = blockIdx.x * 256 + threadIdx.x;
  int l = flat & 63;
  int r = flat >> 6;
  int u = r % 10;
  int r2 = r / 10;          // cbl*16 + w
  int w = r2 & 15;
  int cbl = r2 >> 4;        // 0..63
  int ct = w >> 2, kq = w & 3;
  int kk = (u < 2) ? (2 * kq + u) : (8 + 8 * kq + (u - 2));
  const float* W = (ct == 0) ? Wf : (ct == 1) ? Wi : (ct == 2) ? Wu : Wo;
  int col = cbl * 16 + (l & 15);
  ushort tmp[8];
#pragma unroll
  for (int j = 0; j < 8; ++j) {
    int k = kk * 32 + (l >> 4) * 8 + j;
    tmp[j] = f2bf(W[(size_t)k * H_ + col]);
  }
  *(short8*)(Bp + (size_t)flat * 8) = *(short8*)tmp;
}

// Persistent LSTM, batch-split 4 groups x 64 col-blocks (grid 256).
// Sentinel protocol (FRESH): h slots pre-filled 0xFFFF; consumers stage with
// a plain attempt + sc1 retries; producers publish fire-and-forget sc1 from
// the epilogue waves via in-wave shuffle packing (no drain/flags/3rd barrier).
// gbuf is t-parity double-buffered so waves 4-15 may run ahead into t+1.
template <bool FRESH>
__global__ __launch_bounds__(1024) void lstm_persist(
    const ushort* __restrict__ Xall, const ushort* __restrict__ Bp,
    const float* __restrict__ bfp, const float* __restrict__ bip,
    const float* __restrict__ bup, const float* __restrict__ bop,
    ushort* __restrict__ Hh, float* __restrict__ out,
    unsigned int* __restrict__ flags) {
  __shared__ ushort stg[16][1056];       // 33 KB h(t) slice (64 B row pad)
  __shared__ float gbuf[2][4][4][16][17];// 34.8 KB [par][ct][kq][row][col]
  __shared__ ushort hbuf[16][16][17];    // 8.7 KB out-burst (16 steps)
  const int tid = threadIdx.x;
  const int w = tid >> 6, l = tid & 63;
  const int ct = w >> 2, kq = w & 3;
  const int ar = l & 15, kg = l >> 4;
  const int g = blockIdx.x & 3, cbl = blockIdx.x >> 2;

  short8 bfrag[10];
  {
    const ushort* bp0 = Bp + (((size_t)(cbl * 16 + w) * 10) * 64 + l) * 8;
#pragma unroll
    for (int u = 0; u < 10; ++u) bfrag[u] = *(const short8*)(bp0 + (size_t)u * 512);
  }
#pragma unroll
  for (int u = 0; u < 10; ++u) asm volatile("" : "+v"(bfrag[u]));

  const int b_ep = tid >> 4, hc16 = tid & 15;  // epilogue ids (tid<256)
  float biasF = 0, biasI = 0, biasU = 0, biasO = 0, creg = 0;
  if (tid < 256) {
    int c = cbl * 16 + hc16;
    biasF = bfp[c]; biasI = bip[c]; biasU = bup[c]; biasO = bop[c];
  }

  for (int t = 0; t < T_; ++t) {
    const int pt = t & 1;
    // ---- issue h(t) plain loads FIRST (latency overlaps x-part) ----
    const u64* hp = (const u64*)(Hh +
        ((size_t)(FRESH ? t : pt) * 4 + g) * 16384 + (size_t)w * 1024);
    u64 q0, q1, q2, q3;
    if (t > 0 && FRESH) {
      q0 = hp[2 * l]; q1 = hp[2 * l + 1];
      q2 = hp[128 + 2 * l]; q3 = hp[129 + 2 * l];
    }
    // ---- x-part: 2 MFMAs (kk = 2kq, 2kq+1) ----
    const ushort* xrow = Xall + ((size_t)t * B_ + 16 * g + ar) * 256 + kg * 8;
    float4_ a0 = {0.f, 0.f, 0.f, 0.f}, a1 = {0.f, 0.f, 0.f, 0.f};
    {
      short8 av0 = *(const short8*)(xrow + (2 * kq) * 32);
      short8 av1 = *(const short8*)(xrow + (2 * kq + 1) * 32);
      a0 = __builtin_amdgcn_mfma_f32_16x16x32_bf16(av0, bfrag[0], a0, 0, 0, 0);
      a1 = __builtin_amdgcn_mfma_f32_16x16x32_bf16(av1, bfrag[1], a1, 0, 0, 0);
    }
    if (t > 0) {
      if (FRESH) {
        while (hasS(q0 | q1 | q2 | q3)) {
          __builtin_amdgcn_s_sleep(1);  // sc1 retries bypass L1/L2
          q0 = __hip_atomic_load(hp + 2 * l, __ATOMIC_RELAXED, __HIP_MEMORY_SCOPE_AGENT);
          q1 = __hip_atomic_load(hp + 2 * l + 1, __ATOMIC_RELAXED, __HIP_MEMORY_SCOPE_AGENT);
          q2 = __hip_atomic_load(hp + 128 + 2 * l, __ATOMIC_RELAXED, __HIP_MEMORY_SCOPE_AGENT);
          q3 = __hip_atomic_load(hp + 129 + 2 * l, __ATOMIC_RELAXED, __HIP_MEMORY_SCOPE_AGENT);
        }
      } else {  // flag protocol fallback
        if (tid < 64) {
          unsigned int tgt = (unsigned int)t;
          while (true) {
            unsigned int f0 = __hip_atomic_load(&flags[g * 64 + l], __ATOMIC_RELAXED,
                                                __HIP_MEMORY_SCOPE_AGENT);
            if (__all(f0 >= tgt)) break;
            __builtin_amdgcn_s_sleep(1);
          }
          asm volatile("" ::: "memory");
        }
        __syncthreads();
        q0 = __hip_atomic_load(hp + 2 * l, __ATOMIC_RELAXED, __HIP_MEMORY_SCOPE_AGENT);
        q1 = __hip_atomic_load(hp + 2 * l + 1, __ATOMIC_RELAXED, __HIP_MEMORY_SCOPE_AGENT);
        q2 = __hip_atomic_load(hp + 128 + 2 * l, __ATOMIC_RELAXED, __HIP_MEMORY_SCOPE_AGENT);
        q3 = __hip_atomic_load(hp + 129 + 2 * l, __ATOMIC_RELAXED, __HIP_MEMORY_SCOPE_AGENT);
      }
      {
        union { u64 q[2]; short8 s; } c0, c1;
        c0.q[0] = q0; c0.q[1] = q1; c1.q[0] = q2; c1.q[1] = q3;
        *(short8*)&stg[w][l * 8] = c0.s;
        *(short8*)&stg[w][512 + l * 8] = c1.s;
      }
      __syncthreads();
      // ---- h-part: 8 MFMAs from LDS ----
#pragma unroll
      for (int u = 2; u < 10; ++u) {
        int kk = 8 + 8 * kq + (u - 2);
        short8 av = *(const short8*)&stg[ar][(kk - 8) * 32 + kg * 8];
        if (u & 1) a1 = __builtin_amdgcn_mfma_f32_16x16x32_bf16(av, bfrag[u], a1, 0, 0, 0);
        else       a0 = __builtin_amdgcn_mfma_f32_16x16x32_bf16(av, bfrag[u], a0, 0, 0, 0);
      }
    }
    float4_ acc = a0 + a1;
#pragma unroll
    for (int r = 0; r < 4; ++r) gbuf[pt][ct][kq][kg * 4 + r][ar] = acc[r];
    __syncthreads();
    // ---- epilogue (waves 0-3): gate math + in-wave packed publish ----
    if (tid < 256) {
      float f  = gbuf[pt][0][0][b_ep][hc16] + gbuf[pt][0][1][b_ep][hc16] +
                 gbuf[pt][0][2][b_ep][hc16] + gbuf[pt][0][3][b_ep][hc16] + biasF;
      float i  = gbuf[pt][1][0][b_ep][hc16] + gbuf[pt][1][1][b_ep][hc16] +
                 gbuf[pt][1][2][b_ep][hc16] + gbuf[pt][1][3][b_ep][hc16] + biasI;
      float uu = gbuf[pt][2][0][b_ep][hc16] + gbuf[pt][2][1][b_ep][hc16] +
                 gbuf[pt][2][2][b_ep][hc16] + gbuf[pt][2][3][b_ep][hc16] + biasU;
      float o  = gbuf[pt][3][0][b_ep][hc16] + gbuf[pt][3][1][b_ep][hc16] +
                 gbuf[pt][3][2][b_ep][hc16] + gbuf[pt][3][3][b_ep][hc16] + biasO;
      creg = fmaf(creg, sigm(f), sigm(i) * tanh_fast(uu));
      float h = sigm(o) * tanh_fast(creg);
      ushort hv = f2bf(h);
      // pack 4 lanes' bf16 into u64 via in-wave shuffles; lanes l%4==0 store
      unsigned int hw = hv;
      unsigned int h1 = __shfl_down(hw, 1);
      unsigned int h2 = __shfl_down(hw, 2);
      unsigned int h3 = __shfl_down(hw, 3);
      if ((l & 3) == 0) {
        u64 q = (u64)hw | ((u64)h1 << 16) | ((u64)h2 << 32) | ((u64)h3 << 48);
        u64* dst = (u64*)(Hh +
            ((size_t)(FRESH ? (t + 1) : ((t + 1) & 1)) * 4 + g) * 16384 +
            (size_t)b_ep * 1024 + cbl * 16 + hc16);
        __hip_atomic_store(dst, q, __ATOMIC_RELAXED, __HIP_MEMORY_SCOPE_AGENT);
      }
      hbuf[b_ep][hc16][t & 15] = hv;
      if ((t & 15) == 15) {  // 64 B line-exact burst per thread
        float* orow = out + ((size_t)(16 * g + b_ep) * H_ + cbl * 16 + hc16) * T_ + (t - 15);
#pragma unroll
        for (int tt = 0; tt < 16; tt += 4) {
          float4 v = {bf2f(hbuf[b_ep][hc16][tt]), bf2f(hbuf[b_ep][hc16][tt + 1]),
                      bf2f(hbuf[b_ep][hc16][tt + 2]), bf2f(hbuf[b_ep][hc16][tt + 3])};
          *(float4*)(orow + tt) = v;
        }
      }
    }
    if (!FRESH) {
      asm volatile("s_waitcnt vmcnt(0)" ::: "memory");
      __syncthreads();
      if (tid == 0)
        __hip_atomic_store(&flags[g * 64 + cbl], (unsigned int)(t + 1), __ATOMIC_RELAXED,
                           __HIP_MEMORY_SCOPE_AGENT);
    }
  }
  // ---- final c ----
  if (tid < 256)
    out[(size_t)B_ * H_ * T_ + (size_t)(16 * g + b_ep) * H_ + cbl * 16 + hc16] = creg;
}

extern "C" void kernel_launch(void* const* d_in, const int* in_sizes, int n_in,
                              void* d_out, int out_size, void* d_ws, size_t ws_size,
                              hipStream_t stream) {
  const float* x  = (const float*)d_in[0];
  const float* y  = (const float*)d_in[2];
  const float* Wf = (const float*)d_in[3];  const float* bf = (const float*)d_in[4];
  const float* Wi = (const float*)d_in[5];  const float* bi = (const float*)d_in[6];
  const float* Wu = (const float*)d_in[7];  const float* bu = (const float*)d_in[8];
  const float* Wo = (const float*)d_in[9];  const float* bo = (const float*)d_in[10];
  float* out = (float*)d_out;

  char* p = (char*)d_ws;
  ushort* Bp = (ushort*)p;        p += (size_t)64 * 16 * 10 * 64 * 8 * 2;  // 10.49 MB
  ushort* Xall = (ushort*)p;      p += (size_t)T_ * B_ * 256 * 2;          // 8.39 MB
  unsigned int* flags = (unsigned int*)p; p += 4096;
  ushort* Hh = (ushort*)p;        // FRESH: (T+1) x 4 x 32 KB = 33.6 MB
  size_t head = (size_t)(p - (char*)d_ws);
  bool fresh = ws_size >= head + (size_t)(T_ + 1) * 4 * 16384 * 2;

  prep_weights<<<(64 * 16 * 10 * 64) / 256, 256, 0, stream>>>(Wf, Wi, Wu, Wo, Bp);
  build_X<<<B_ * 8, 256, 0, stream>>>(x, y, Xall);
  if (fresh) {
    // re-arm sentinels every call (graph replays leave old h values behind)
    (void)hipMemsetAsync(Hh, 0xFF, (size_t)(T_ + 1) * 4 * 16384 * 2, stream);
  } else {
    (void)hipMemsetAsync(flags, 0, 4096, stream);
    (void)hipMemsetAsync(Hh, 0, (size_t)2 * 4 * 16384 * 2, stream);
  }

  if (fresh)
    lstm_persist<true><<<NB_, 1024, 0, stream>>>(Xall, Bp, bf, bi, bu, bo, Hh, out, flags);
  else
    lstm_persist<false><<<NB_, 1024, 0, stream>>>(Xall, Bp, bf, bi, bu, bo, Hh, out, flags);
}

// Round 14
// 714.677 us; speedup vs baseline: 1.4560x; 1.4560x over previous
//
#include <hip/hip_runtime.h>
#include <hip/hip_bf16.h>

#define B_ 64
#define T_ 256
#define H_ 1024
#define NB_ 256  // 4 groups x 64 col-blocks

typedef __attribute__((ext_vector_type(8))) short short8;
typedef __attribute__((ext_vector_type(4))) float float4_;
typedef unsigned long long u64;

static __device__ __forceinline__ ushort f2bf(float v) {
  __hip_bfloat16 b = __float2bfloat16(v);
  return *reinterpret_cast<ushort*>(&b);
}
static __device__ __forceinline__ float bf2f(ushort u) {
  unsigned int x = ((unsigned int)u) << 16;
  return __builtin_bit_cast(float, x);
}
static __device__ __forceinline__ float sigm(float v) { return 1.0f / (1.0f + __expf(-v)); }
static __device__ __forceinline__ float tanh_fast(float v) {
  float e = __expf(2.0f * v);
  return 1.0f - 2.0f / (e + 1.0f);
}
// sentinel = 0xFFFF (bf16 -NaN). |h| < 1 -> data bf16 never sets bit14
// (needs exponent >= 128, i.e. |h| >= 2); the sentinel always does. So a
// sentinel in ANY word of the OR shows up as bit14 somewhere.
static __device__ __forceinline__ bool anyS(u64 q) {
  return (q & 0x4000400040004000ull) != 0ull;
}

// Xall[t][b][j] bf16: j even = x[b][j/2][t], j odd = y[b][j/2][t-1] (0 at t=0)
__global__ __launch_bounds__(256) void build_X(const float* __restrict__ x,
                                               const float* __restrict__ y,
                                               ushort* __restrict__ Xall) {
  __shared__ float xl[128][33];
  __shared__ float yl[128][33];
  int b = blockIdx.x >> 3;
  int t0 = (blockIdx.x & 7) * 32;
  int tid = threadIdx.x;
  for (int it = 0; it < 16; ++it) {
    int idx = it * 256 + tid;
    int s = idx >> 5, tt = idx & 31;
    xl[s][tt] = x[((size_t)b * 128 + s) * T_ + t0 + tt];
    int ty = t0 + tt - 1;
    yl[s][tt] = (ty >= 0) ? y[((size_t)b * 128 + s) * T_ + ty] : 0.0f;
  }
  __syncthreads();
  for (int tt = 0; tt < 32; ++tt) {
    float v = (tid & 1) ? yl[tid >> 1][tt] : xl[tid >> 1][tt];
    Xall[((size_t)(t0 + tt) * B_ + b) * 256 + tid] = f2bf(v);
  }
}

// Bp[(((cbl*16 + w)*10 + u)*64 + l)*8 + j]
// wave w = ct*4+kq; frag u: kk = (u<2)? 2kq+u : 8+8kq+(u-2)
// lane l: B[k = 32kk + 8*(l>>4) + j][col_in_gate = cbl*16 + (l&15)], gate ct
__global__ __launch_bounds__(256) void prep_weights(const float* __restrict__ Wf,
                                                    const float* __restrict__ Wi,
                                                    const float* __restrict__ Wu,
                                                    const float* __restrict__ Wo,
                                                    ushort* __restrict__ Bp) {
  int flat = blockIdx.x * 256 + threadIdx.x;
  int l = flat & 63;
  int r = flat >> 6;
  int u = r % 10;
  int r2 = r / 10;          // cbl*16 + w
  int w = r2 & 15;
  int cbl = r2 >> 4;        // 0..63
  int ct = w >> 2, kq = w & 3;
  int kk = (u < 2) ? (2 * kq + u) : (8 + 8 * kq + (u - 2));
  const float* W = (ct == 0) ? Wf : (ct == 1) ? Wi : (ct == 2) ? Wu : Wo;
  int col = cbl * 16 + (l & 15);
  ushort tmp[8];
#pragma unroll
  for (int j = 0; j < 8; ++j) {
    int k = kk * 32 + (l >> 4) * 8 + j;
    tmp[j] = f2bf(W[(size_t)k * H_ + col]);
  }
  *(short8*)(Bp + (size_t)flat * 8) = *(short8*)tmp;
}

// Persistent LSTM, batch-split 4 groups x 64 col-blocks (grid 256).
// Sentinel protocol (FRESH): h slots pre-filled 0xFFFF; consumers stage with
// a plain attempt (after the x-part, round-12 alignment) + sc1 retries;
// producers publish fire-and-forget sc1 directly from the epilogue via
// in-wave shuffle packing. The trailing __syncthreads HOLDS THE HERD so
// no wave starts next-t sentinel spinning before publishes are issued.
template <bool FRESH>
__global__ __launch_bounds__(1024) void lstm_persist(
    const ushort* __restrict__ Xall, const ushort* __restrict__ Bp,
    const float* __restrict__ bfp, const float* __restrict__ bip,
    const float* __restrict__ bup, const float* __restrict__ bop,
    ushort* __restrict__ Hh, float* __restrict__ out,
    unsigned int* __restrict__ flags) {
  __shared__ ushort stg[16][1056];     // 33 KB h(t) slice (64 B row pad)
  __shared__ float gbuf[4][4][16][17]; // 17.4 KB [ct][kq][row][col]
  __shared__ ushort hbuf[16][16][17];  // 8.7 KB out-burst (16 steps)
  const int tid = threadIdx.x;
  const int w = tid >> 6, l = tid & 63;
  const int ct = w >> 2, kq = w & 3;
  const int ar = l & 15, kg = l >> 4;
  const int g = blockIdx.x & 3, cbl = blockIdx.x >> 2;

  short8 bfrag[10];
  {
    const ushort* bp0 = Bp + (((size_t)(cbl * 16 + w) * 10) * 64 + l) * 8;
#pragma unroll
    for (int u = 0; u < 10; ++u) bfrag[u] = *(const short8*)(bp0 + (size_t)u * 512);
  }
#pragma unroll
  for (int u = 0; u < 10; ++u) asm volatile("" : "+v"(bfrag[u]));

  const int b_ep = tid >> 4, hc16 = tid & 15;  // epilogue ids (tid<256)
  float biasF = 0, biasI = 0, biasU = 0, biasO = 0, creg = 0;
  if (tid < 256) {
    int c = cbl * 16 + hc16;
    biasF = bfp[c]; biasI = bip[c]; biasU = bup[c]; biasO = bop[c];
  }

  for (int t = 0; t < T_; ++t) {
    // ---- x-part: 2 MFMAs (kk = 2kq, 2kq+1) ----
    const ushort* xrow = Xall + ((size_t)t * B_ + 16 * g + ar) * 256 + kg * 8;
    float4_ a0 = {0.f, 0.f, 0.f, 0.f}, a1 = {0.f, 0.f, 0.f, 0.f};
    {
      short8 av0 = *(const short8*)(xrow + (2 * kq) * 32);
      short8 av1 = *(const short8*)(xrow + (2 * kq + 1) * 32);
      a0 = __builtin_amdgcn_mfma_f32_16x16x32_bf16(av0, bfrag[0], a0, 0, 0, 0);
      a1 = __builtin_amdgcn_mfma_f32_16x16x32_bf16(av1, bfrag[1], a1, 0, 0, 0);
    }
    if (t > 0) {
      if (!FRESH) {  // flag protocol fallback
        if (tid < 64) {
          unsigned int tgt = (unsigned int)t;
          while (true) {
            unsigned int f0 = __hip_atomic_load(&flags[g * 64 + l], __ATOMIC_RELAXED,
                                                __HIP_MEMORY_SCOPE_AGENT);
            if (__all(f0 >= tgt)) break;
            __builtin_amdgcn_s_sleep(1);
          }
          asm volatile("" ::: "memory");
        }
        __syncthreads();
      }
      // ---- stage row w of h(t): plain attempt + sc1 retries ----
      {
        const u64* p = (const u64*)(Hh +
            ((size_t)(FRESH ? t : (t & 1)) * 4 + g) * 16384 + (size_t)w * 1024);
        u64 q0, q1, q2, q3;
        if (FRESH) {
          q0 = p[2 * l]; q1 = p[2 * l + 1];          // plain: L2-amortized
          q2 = p[128 + 2 * l]; q3 = p[129 + 2 * l];
          while (anyS(q0 | q1 | q2 | q3)) {
            __builtin_amdgcn_s_sleep(1);             // sc1 retries (L1/L2 bypass)
            q0 = __hip_atomic_load(p + 2 * l, __ATOMIC_RELAXED, __HIP_MEMORY_SCOPE_AGENT);
            q1 = __hip_atomic_load(p + 2 * l + 1, __ATOMIC_RELAXED, __HIP_MEMORY_SCOPE_AGENT);
            q2 = __hip_atomic_load(p + 128 + 2 * l, __ATOMIC_RELAXED, __HIP_MEMORY_SCOPE_AGENT);
            q3 = __hip_atomic_load(p + 129 + 2 * l, __ATOMIC_RELAXED, __HIP_MEMORY_SCOPE_AGENT);
          }
        } else {
          q0 = __hip_atomic_load(p + 2 * l, __ATOMIC_RELAXED, __HIP_MEMORY_SCOPE_AGENT);
          q1 = __hip_atomic_load(p + 2 * l + 1, __ATOMIC_RELAXED, __HIP_MEMORY_SCOPE_AGENT);
          q2 = __hip_atomic_load(p + 128 + 2 * l, __ATOMIC_RELAXED, __HIP_MEMORY_SCOPE_AGENT);
          q3 = __hip_atomic_load(p + 129 + 2 * l, __ATOMIC_RELAXED, __HIP_MEMORY_SCOPE_AGENT);
        }
        union { u64 q[2]; short8 s; } c0, c1;
        c0.q[0] = q0; c0.q[1] = q1; c1.q[0] = q2; c1.q[1] = q3;
        *(short8*)&stg[w][l * 8] = c0.s;
        *(short8*)&stg[w][512 + l * 8] = c1.s;
      }
      __syncthreads();
      // ---- h-part: 8 MFMAs from LDS (identity layout) ----
#pragma unroll
      for (int u = 2; u < 10; ++u) {
        int kk = 8 + 8 * kq + (u - 2);
        short8 av = *(const short8*)&stg[ar][(kk - 8) * 32 + kg * 8];
        if (u & 1) a1 = __builtin_amdgcn_mfma_f32_16x16x32_bf16(av, bfrag[u], a1, 0, 0, 0);
        else       a0 = __builtin_amdgcn_mfma_f32_16x16x32_bf16(av, bfrag[u], a0, 0, 0, 0);
      }
    }
    float4_ acc = a0 + a1;
#pragma unroll
    for (int r = 0; r < 4; ++r) gbuf[ct][kq][kg * 4 + r][ar] = acc[r];
    __syncthreads();
    // ---- epilogue: 256 threads own one (b, hcol); publish fused ----
    if (tid < 256) {
      float f  = gbuf[0][0][b_ep][hc16] + gbuf[0][1][b_ep][hc16] +
                 gbuf[0][2][b_ep][hc16] + gbuf[0][3][b_ep][hc16] + biasF;
      float i  = gbuf[1][0][b_ep][hc16] + gbuf[1][1][b_ep][hc16] +
                 gbuf[1][2][b_ep][hc16] + gbuf[1][3][b_ep][hc16] + biasI;
      float uu = gbuf[2][0][b_ep][hc16] + gbuf[2][1][b_ep][hc16] +
                 gbuf[2][2][b_ep][hc16] + gbuf[2][3][b_ep][hc16] + biasU;
      float o  = gbuf[3][0][b_ep][hc16] + gbuf[3][1][b_ep][hc16] +
                 gbuf[3][2][b_ep][hc16] + gbuf[3][3][b_ep][hc16] + biasO;
      creg = fmaf(creg, sigm(f), sigm(i) * tanh_fast(uu));
      float h = sigm(o) * tanh_fast(creg);
      ushort hv = f2bf(h);
      // publish: pack 4 lanes' bf16 via in-wave shuffles; l%4==0 stores 8 B
      unsigned int hw = hv;
      unsigned int h1 = __shfl_down(hw, 1);
      unsigned int h2 = __shfl_down(hw, 2);
      unsigned int h3 = __shfl_down(hw, 3);
      if ((l & 3) == 0) {
        u64 q = (u64)hw | ((u64)h1 << 16) | ((u64)h2 << 32) | ((u64)h3 << 48);
        u64* dst = (u64*)(Hh +
            ((size_t)(FRESH ? (t + 1) : ((t + 1) & 1)) * 4 + g) * 16384 +
            (size_t)b_ep * 1024 + cbl * 16 + hc16);
        __hip_atomic_store(dst, q, __ATOMIC_RELAXED, __HIP_MEMORY_SCOPE_AGENT);
      }
      hbuf[b_ep][hc16][t & 15] = hv;
      if ((t & 15) == 15) {  // 64 B line-exact burst per thread
        float* orow = out + ((size_t)(16 * g + b_ep) * H_ + cbl * 16 + hc16) * T_ + (t - 15);
#pragma unroll
        for (int tt = 0; tt < 16; tt += 4) {
          float4 v = {bf2f(hbuf[b_ep][hc16][tt]), bf2f(hbuf[b_ep][hc16][tt + 1]),
                      bf2f(hbuf[b_ep][hc16][tt + 2]), bf2f(hbuf[b_ep][hc16][tt + 3])};
          *(float4*)(orow + tt) = v;
        }
      }
    }
    // herd-hold: nobody starts next-t sentinel spinning before publishes
    // of this block are issued (round-13 congestion lesson)
    __syncthreads();
    if (!FRESH) {
      asm volatile("s_waitcnt vmcnt(0)" ::: "memory");
      __syncthreads();
      if (tid == 0)
        __hip_atomic_store(&flags[g * 64 + cbl], (unsigned int)(t + 1), __ATOMIC_RELAXED,
                           __HIP_MEMORY_SCOPE_AGENT);
    }
  }
  // ---- final c ----
  if (tid < 256)
    out[(size_t)B_ * H_ * T_ + (size_t)(16 * g + b_ep) * H_ + cbl * 16 + hc16] = creg;
}

extern "C" void kernel_launch(void* const* d_in, const int* in_sizes, int n_in,
                              void* d_out, int out_size, void* d_ws, size_t ws_size,
                              hipStream_t stream) {
  const float* x  = (const float*)d_in[0];
  const float* y  = (const float*)d_in[2];
  const float* Wf = (const float*)d_in[3];  const float* bf = (const float*)d_in[4];
  const float* Wi = (const float*)d_in[5];  const float* bi = (const float*)d_in[6];
  const float* Wu = (const float*)d_in[7];  const float* bu = (const float*)d_in[8];
  const float* Wo = (const float*)d_in[9];  const float* bo = (const float*)d_in[10];
  float* out = (float*)d_out;

  char* p = (char*)d_ws;
  ushort* Bp = (ushort*)p;        p += (size_t)64 * 16 * 10 * 64 * 8 * 2;  // 10.49 MB
  ushort* Xall = (ushort*)p;      p += (size_t)T_ * B_ * 256 * 2;          // 8.39 MB
  unsigned int* flags = (unsigned int*)p; p += 4096;
  ushort* Hh = (ushort*)p;        // FRESH: (T+1) x 4 x 32 KB = 33.6 MB
  size_t head = (size_t)(p - (char*)d_ws);
  bool fresh = ws_size >= head + (size_t)(T_ + 1) * 4 * 16384 * 2;

  prep_weights<<<(64 * 16 * 10 * 64) / 256, 256, 0, stream>>>(Wf, Wi, Wu, Wo, Bp);
  build_X<<<B_ * 8, 256, 0, stream>>>(x, y, Xall);
  if (fresh) {
    // re-arm sentinels every call (graph replays leave old h values behind)
    (void)hipMemsetAsync(Hh, 0xFF, (size_t)(T_ + 1) * 4 * 16384 * 2, stream);
  } else {
    (void)hipMemsetAsync(flags, 0, 4096, stream);
    (void)hipMemsetAsync(Hh, 0, (size_t)2 * 4 * 16384 * 2, stream);
  }

  if (fresh)
    lstm_persist<true><<<NB_, 1024, 0, stream>>>(Xall, Bp, bf, bi, bu, bo, Hh, out, flags);
  else
    lstm_persist<false><<<NB_, 1024, 0, stream>>>(Xall, Bp, bf, bi, bu, bo, Hh, out, flags);
}